// Round 4
// baseline (5344.179 us; speedup 1.0000x reference)
//
#include <hip/hip_runtime.h>
#include <math.h>

// Semi-relaxed Sinkhorn-Knopp, MI355X. B=16, n=4096, k=1024, K=1025.
// R3: ONE kernel launch per iteration. Each block computes row a-updates +
// column partials for 64 rows; partials published with agent-scope relaxed
// atomic stores (coherence-point visibility, no fences); the last 256 blocks
// to finish (ticket >= NBLK-256) spin until all partials are in, then do the
// distributed b-update + err + flag inside the same launch. Iteration 0
// computes Q from logits inline (prep folded in). Plan recomputes fp32 Q.

namespace {
constexpr int   Bn      = 16;
constexpr int   Kc      = 1024;    // k
constexpr int   KK      = 1025;    // K = k+1 (dustbin)
constexpr int   BSTR    = 1028;    // padded b stride
constexpr int   ROWS    = 65536;   // B*n
constexpr int   NBLK    = 1024;    // iter blocks, 64 rows each
constexpr int   NFIN    = 256;     // late blocks that run the fin phase
constexpr float INV_EPS = 10.0f;
constexpr float PA      = 1.0f / 4096.0f;
constexpr float PB_LOW  = (float)(0.5 / 1024.0);
constexpr float PB_DUST = 0.5f;
constexpr float FI_F    = (float)(1.0 / 1.1); // GAMMA/(GAMMA+EPS)
constexpr float STOP    = 1e-6f;
constexpr int   NITER   = 100;
} // namespace

typedef __attribute__((ext_vector_type(8))) unsigned short ushort8;

#define LOADX(p)    __hip_atomic_load((p), __ATOMIC_RELAXED, __HIP_MEMORY_SCOPE_AGENT)
#define STOREX(p,v) __hip_atomic_store((p), (v), __ATOMIC_RELAXED, __HIP_MEMORY_SCOPE_AGENT)

__device__ __forceinline__ float wredsum(float v) {
#pragma unroll
  for (int m = 32; m >= 1; m >>= 1) v += __shfl_xor(v, m, 64);
  return v;
}
__device__ __forceinline__ float wredmax(float v) {
#pragma unroll
  for (int m = 32; m >= 1; m >>= 1) v = fmaxf(v, __shfl_xor(v, m, 64));
  return v;
}
__device__ __forceinline__ unsigned short f2bf(float x) {
  unsigned int u = __float_as_uint(x);
  return (unsigned short)((u + 0x7FFFu + ((u >> 16) & 1u)) >> 16);  // RNE
}
__device__ __forceinline__ float bf2f(unsigned short h) {
  return __uint_as_float(((unsigned int)h) << 16);
}

// ---------------- init ----------------
__global__ void k_init(float* __restrict__ bvec, float* __restrict__ e2acc,
                       int* __restrict__ cnt, int* __restrict__ cnt2,
                       int* __restrict__ flag) {
  int tid = blockIdx.x * blockDim.x + threadIdx.x;
  int stride = gridDim.x * blockDim.x;
  for (int i = tid; i < Bn * BSTR; i += stride) {
    int j = i % BSTR;
    bvec[i] = (j < KK) ? (float)(1.0 / 1025.0) : 0.0f;
  }
  for (int i = tid; i < NITER; i += stride) {
    e2acc[i] = 0.0f; cnt[i] = 0; cnt2[i] = 0;
  }
  if (tid == 0) *flag = 1;
}

// ---------------- fused iteration (+fin inside) ----------------
template <bool FIRST>
__global__ __launch_bounds__(256, 4) void k_iter(
    const float* __restrict__ x, unsigned short* __restrict__ Qb,
    float* __restrict__ bvec, float* __restrict__ avec,
    float* __restrict__ part, float* __restrict__ sumaPart,
    float* __restrict__ e2acc, int* __restrict__ cnt, int* __restrict__ cnt2,
    int* __restrict__ flag, int it) {
  __shared__ float cpart[4][1024];
  __shared__ float sred[4];
  __shared__ int shi;
  const int tid = threadIdx.x, wid = tid >> 6, lane = tid & 63;
  if (tid == 0) shi = *flag;
  __syncthreads();
  if (shi == 0) return;

  const int blk = blockIdx.x;
  const int baseRow = blk * 64;
  const int batch = baseRow >> 12;

  const float4* bp = (const float4*)(bvec + batch * BSTR);
  float4 bb[4];
#pragma unroll
  for (int s = 0; s < 4; ++s) bb[s] = bp[lane * 4 + s];
  const float bdust = bvec[batch * BSTR + 1024];

  float acc[16];
#pragma unroll
  for (int e = 0; e < 16; ++e) acc[e] = 0.0f;
  float sal = 0.0f;

  const int rowBase = baseRow + wid * 16;
#pragma unroll 4
  for (int r = 0; r < 16; ++r) {
    float q[16];
    if constexpr (FIRST) {
      const float4* xp = (const float4*)(x + ((size_t)(rowBase + r) << 10));
      float4 v[4];
#pragma unroll
      for (int s = 0; s < 4; ++s) v[s] = xp[lane * 4 + s];
      float m = -1e30f;
#pragma unroll
      for (int s = 0; s < 4; ++s)
        m = fmaxf(m, fmaxf(fmaxf(v[s].x, v[s].y), fmaxf(v[s].z, v[s].w)));
      m = wredmax(m);
      float su = 0.0f;
#pragma unroll
      for (int s = 0; s < 4; ++s)
        su += expf(v[s].x - m) + expf(v[s].y - m) + expf(v[s].z - m) + expf(v[s].w - m);
      su = wredsum(su);
      const float lse = m + logf(su);
      ushort8 qa, qb2;
#pragma unroll
      for (int s = 0; s < 4; ++s) {
        const unsigned short u0 = f2bf(expf((v[s].x - lse) * INV_EPS));
        const unsigned short u1 = f2bf(expf((v[s].y - lse) * INV_EPS));
        const unsigned short u2 = f2bf(expf((v[s].z - lse) * INV_EPS));
        const unsigned short u3 = f2bf(expf((v[s].w - lse) * INV_EPS));
        if (s < 2) { qa[s*4+0]=u0; qa[s*4+1]=u1; qa[s*4+2]=u2; qa[s*4+3]=u3; }
        else { qb2[(s-2)*4+0]=u0; qb2[(s-2)*4+1]=u1; qb2[(s-2)*4+2]=u2; qb2[(s-2)*4+3]=u3; }
        q[s*4+0]=bf2f(u0); q[s*4+1]=bf2f(u1); q[s*4+2]=bf2f(u2); q[s*4+3]=bf2f(u3);
      }
      ushort8* qp = (ushort8*)(Qb + ((size_t)(rowBase + r) << 10));
      qp[lane * 2] = qa; qp[lane * 2 + 1] = qb2;
    } else {
      const ushort8* qp = (const ushort8*)(Qb + ((size_t)(rowBase + r) << 10));
      const ushort8 qa = qp[lane * 2], qb2 = qp[lane * 2 + 1];
#pragma unroll
      for (int e = 0; e < 8; ++e) { q[e] = bf2f(qa[e]); q[8 + e] = bf2f(qb2[e]); }
    }

    float p = 0.0f;
#pragma unroll
    for (int s = 0; s < 4; ++s)
      p += q[s * 4 + 0] * bb[s].x + q[s * 4 + 1] * bb[s].y +
           q[s * 4 + 2] * bb[s].z + q[s * 4 + 3] * bb[s].w;

    const float inner = wredsum(p) + bdust;       // dustbin Q == 1
    const float a = PA / inner;                   // broadcast to all lanes
    if (lane == 0) { avec[rowBase + r] = a; sal += a; }
#pragma unroll
    for (int e = 0; e < 16; ++e) acc[e] += q[e] * a;
  }
  if (lane == 0) sred[wid] = sal;

  float4* cp = (float4*)&cpart[wid][lane * 16];
#pragma unroll
  for (int s = 0; s < 4; ++s)
    cp[s] = make_float4(acc[s * 4 + 0], acc[s * 4 + 1], acc[s * 4 + 2], acc[s * 4 + 3]);
  __syncthreads();

  {
    const int j = tid * 4;
    float* pb = part + ((size_t)blk << 10) + j;
#pragma unroll
    for (int e = 0; e < 4; ++e) {
      const float v = cpart[0][j + e] + cpart[1][j + e] + cpart[2][j + e] + cpart[3][j + e];
      STOREX(pb + e, v);
    }
    if (tid == 0)
      STOREX(&sumaPart[blk], sred[0] + sred[1] + sred[2] + sred[3]);
  }
  __syncthreads();   // s_waitcnt before barrier drains the part stores
  if (tid == 0)
    shi = __hip_atomic_fetch_add(&cnt[it], 1, __ATOMIC_RELAXED, __HIP_MEMORY_SCOPE_AGENT);
  __syncthreads();
  const int ticket = shi;
  if (ticket < NBLK - NFIN) return;   // early blocks exit; <=256 spinners

  // ---------------- fin phase (inside the same launch) ----------------
  if (tid == 0) {
    while (LOADX(&cnt[it]) < NBLK) __builtin_amdgcn_s_sleep(1);
  }
  __syncthreads();

  const int fin_id = ticket - (NBLK - NFIN);   // 0..255
  const int fb = fin_id >> 4;                  // batch
  const int colBase = (fin_id & 15) * 64;      // 64-column slice
  {
    const float* basep = part + (((size_t)(fb * 64 + wid * 16)) << 10) + colBase + lane;
    float s = 0.0f;
#pragma unroll
    for (int j = 0; j < 16; ++j) s += LOADX(basep + ((size_t)j << 10));
    cpart[wid][lane] = s;
  }
  __syncthreads();
  if (wid == 0) {
    const int col = colBase + lane;
    const float s = cpart[0][lane] + cpart[1][lane] + cpart[2][lane] + cpart[3][lane];
    float* bslot = bvec + fb * BSTR + col;
    const float bold = *bslot;
    const float bnew = exp2f(FI_F * log2f(PB_LOW / s));
    *bslot = bnew;
    float e2 = (bnew - bold) * (bnew - bold);

    if ((fin_id & 15) == 0) {                  // this block also does dustbin
      float sa = LOADX(&sumaPart[fb * 64 + lane]);
      sa = wredsum(sa);
      if (lane == 0) {
        float* ds = bvec + fb * BSTR + 1024;
        const float bo = *ds;
        const float bn = PB_DUST / sa;
        *ds = bn;
        e2 += (bn - bo) * (bn - bo);
      }
    }
    const float e2w = wredsum(e2);
    if (lane == 0) {
      __hip_atomic_fetch_add(&e2acc[it], e2w, __ATOMIC_RELAXED, __HIP_MEMORY_SCOPE_AGENT);
      const int t2 = __hip_atomic_fetch_add(&cnt2[it], 1, __ATOMIC_ACQ_REL, __HIP_MEMORY_SCOPE_AGENT);
      if (t2 == NFIN - 1) {
        const float err = sqrtf(LOADX(&e2acc[it]));
        if (!(err > STOP)) STOREX(flag, 0);    // NaN also stops, like jnp
      }
    }
  }
}

// ---------------- plan: recompute fp32 Q from logits; out = a*Q*b*n -------
__global__ __launch_bounds__(256) void k_plan(const float* __restrict__ x,
                                              float* __restrict__ out,
                                              const float* __restrict__ avec,
                                              const float* __restrict__ bvec) {
  const int wid = threadIdx.x >> 6, lane = threadIdx.x & 63;
  const int row = blockIdx.x * 4 + wid;
  const int batch = row >> 12;
  const float4* xp = (const float4*)(x + ((size_t)row << 10));
  float4 v[4];
#pragma unroll
  for (int s = 0; s < 4; ++s) v[s] = xp[lane * 4 + s];

  float m = -1e30f;
#pragma unroll
  for (int s = 0; s < 4; ++s)
    m = fmaxf(m, fmaxf(fmaxf(v[s].x, v[s].y), fmaxf(v[s].z, v[s].w)));
  m = wredmax(m);
  float sum = 0.0f;
#pragma unroll
  for (int s = 0; s < 4; ++s)
    sum += expf(v[s].x - m) + expf(v[s].y - m) + expf(v[s].z - m) + expf(v[s].w - m);
  sum = wredsum(sum);
  const float lse = m + logf(sum);

  const float sc = avec[row] * 4096.0f;
  const float4* bp = (const float4*)(bvec + batch * BSTR);
  float4* op = (float4*)(out + ((size_t)row << 10));
#pragma unroll
  for (int s = 0; s < 4; ++s) {
    const float4 b = bp[lane * 4 + s];
    float4 o;
    o.x = expf((v[s].x - lse) * INV_EPS) * sc * b.x;
    o.y = expf((v[s].y - lse) * INV_EPS) * sc * b.y;
    o.z = expf((v[s].z - lse) * INV_EPS) * sc * b.z;
    o.w = expf((v[s].w - lse) * INV_EPS) * sc * b.w;
    op[lane * 4 + s] = o;
  }
}

extern "C" void kernel_launch(void* const* d_in, const int* in_sizes, int n_in,
                              void* d_out, int out_size, void* d_ws, size_t ws_size,
                              hipStream_t stream) {
  const float* logits = (const float*)d_in[0];
  unsigned short* Qb = (unsigned short*)d_out;   // bf16 Q in first half of d_out
  float* ws = (float*)d_ws;
  float* bvec     = ws;                          // 16*1028
  float* avec     = bvec + Bn * BSTR;            // 65536
  float* part     = avec + ROWS;                 // 1024*1024
  float* sumaPart = part + (size_t)NBLK * Kc;    // 1024
  float* e2acc    = sumaPart + NBLK;             // NITER
  int*   cnt      = (int*)(e2acc + NITER);       // NITER
  int*   cnt2     = cnt + NITER;                 // NITER
  int*   flag     = cnt2 + NITER;                // 1

  k_init<<<64, 256, 0, stream>>>(bvec, e2acc, cnt, cnt2, flag);
  k_iter<true><<<NBLK, 256, 0, stream>>>(logits, Qb, bvec, avec, part, sumaPart,
                                         e2acc, cnt, cnt2, flag, 0);
  for (int it = 1; it < NITER; ++it)
    k_iter<false><<<NBLK, 256, 0, stream>>>(logits, Qb, bvec, avec, part, sumaPart,
                                            e2acc, cnt, cnt2, flag, it);
  k_plan<<<ROWS / 4, 256, 0, stream>>>(logits, (float*)d_out, avec, bvec);
}